// Round 6
// baseline (307.547 us; speedup 1.0000x reference)
//
#include <hip/hip_runtime.h>

#define B_ 4
#define L_ 4096
#define D_ 1152
#define T_ (B_*L_)      // 16384 tokens
#define D3_ 384
#define H_ 16
#define DK3_ 24

typedef __attribute__((ext_vector_type(4))) float f32x4;
typedef __attribute__((ext_vector_type(8))) __bf16 bf16x8;
typedef __attribute__((ext_vector_type(8))) unsigned short u16x8;
typedef __attribute__((ext_vector_type(4))) unsigned short u16x4;

__device__ __forceinline__ unsigned short f2bf(float f) {
  unsigned int u = __float_as_uint(f);
  u += 0x7fffu + ((u >> 16) & 1u);   // round-to-nearest-even
  return (unsigned short)(u >> 16);
}
__device__ __forceinline__ float bf2f(unsigned short h) {
  return __uint_as_float(((unsigned int)h) << 16);
}

// async global->LDS, 16B per lane. LDS dest wave-uniform; lane l writes dest + l*16.
__device__ __forceinline__ void gl_lds16(const unsigned short* g, unsigned short* l) {
  __builtin_amdgcn_global_load_lds(
      (const __attribute__((address_space(1))) unsigned int*)g,
      (__attribute__((address_space(3))) unsigned int*)l,
      16, 0, 0);
}

// ---------------- LayerNorm: fp32 [16384,1152] -> bf16 [16384,1152] ----------------
__global__ __launch_bounds__(256) void ln_kernel(const float* __restrict__ x,
                                                 const float* __restrict__ gamma,
                                                 const float* __restrict__ beta,
                                                 unsigned short* __restrict__ xn) {
  const int row = blockIdx.x;
  const int tid = threadIdx.x;
  const float4* xr = (const float4*)(x + (size_t)row * D_);
  float4 v0 = xr[tid];
  float4 v1 = {0.f, 0.f, 0.f, 0.f};
  const bool has2 = tid < 32;
  if (has2) v1 = xr[256 + tid];
  float s  = v0.x + v0.y + v0.z + v0.w + v1.x + v1.y + v1.z + v1.w;
  float s2 = v0.x*v0.x + v0.y*v0.y + v0.z*v0.z + v0.w*v0.w
           + v1.x*v1.x + v1.y*v1.y + v1.z*v1.z + v1.w*v1.w;
#pragma unroll
  for (int o = 32; o > 0; o >>= 1) { s += __shfl_down(s, o); s2 += __shfl_down(s2, o); }
  __shared__ float red[8];
  int wid = tid >> 6, lane = tid & 63;
  if (lane == 0) { red[wid] = s; red[4 + wid] = s2; }
  __syncthreads();
  float ts  = red[0] + red[1] + red[2] + red[3];
  float ts2 = red[4] + red[5] + red[6] + red[7];
  const float inv = 1.f / (float)D_;
  float mean = ts * inv;
  float var  = ts2 * inv - mean * mean;
  float rstd = rsqrtf(var + 1e-6f);
  const float4* gm = (const float4*)gamma;
  const float4* bt = (const float4*)beta;
  unsigned short* xo = xn + (size_t)row * D_;
  {
    float4 gv = gm[tid], bv = bt[tid];
    u16x4 r;
    r[0] = f2bf((v0.x - mean) * rstd * gv.x + bv.x);
    r[1] = f2bf((v0.y - mean) * rstd * gv.y + bv.y);
    r[2] = f2bf((v0.z - mean) * rstd * gv.z + bv.z);
    r[3] = f2bf((v0.w - mean) * rstd * gv.w + bv.w);
    *(u16x4*)(xo + tid * 4) = r;
  }
  if (has2) {
    float4 gv = gm[256 + tid], bv = bt[256 + tid];
    u16x4 r;
    r[0] = f2bf((v1.x - mean) * rstd * gv.x + bv.x);
    r[1] = f2bf((v1.y - mean) * rstd * gv.y + bv.y);
    r[2] = f2bf((v1.z - mean) * rstd * gv.z + bv.z);
    r[3] = f2bf((v1.w - mean) * rstd * gv.w + bv.w);
    *(u16x4*)(xo + (256 + tid) * 4) = r;
  }
}

// ---------------- Weight converts ----------------
__global__ void cvt_cat_wqkvg(const float* __restrict__ Wq, const float* __restrict__ Wk,
                              const float* __restrict__ Wv, const float* __restrict__ Wg,
                              unsigned short* __restrict__ out) {
  int i = blockIdx.x * 256 + threadIdx.x;
  if (i >= 4 * 147456) return;
  int p = i / 147456;
  int r = i - p * 147456;
  const float* W = (p == 0) ? Wq : (p == 1) ? Wk : (p == 2) ? Wv : Wg;
  out[i] = f2bf(W[r]);
}

__global__ void cvt_bf16(const float* __restrict__ in, unsigned short* __restrict__ out, int n) {
  int i = blockIdx.x * 256 + threadIdx.x;
  if (i < n) out[i] = f2bf(in[i]);
}

// ---------------- bf16 GEMM: C[M,N] = A[M,K] @ Bt[N,K]^T (+epilogue) ----------------
// 128x128 tile, BK=32, 4 waves (2x2), 4x4 16x16x32 frags/wave.
// 3-deep LDS ring + counted vmcnt (T4). SWAPPED mfma operands -> transposed D:
// lane reg-quad = 4 consecutive OUTPUT COLS -> vectorized u16x4 / float4 epilogue.
// XCD-exclusive bm partition: each XCD owns a contiguous bm range, bn fastest.

template<int EPI>
__global__ __launch_bounds__(256) void gemm_bt(
    const unsigned short* __restrict__ A, const unsigned short* __restrict__ Bt,
    int K, int N,
    unsigned short* __restrict__ Cb,
    const float* __restrict__ b0, const float* __restrict__ b1,
    const float* __restrict__ b2, const float* __restrict__ b3,
    float* __restrict__ Cf, const float* __restrict__ bo,
    const float* __restrict__ xres, const float* __restrict__ gs) {
  __shared__ __align__(16) unsigned short As[3][128 * 32];
  __shared__ __align__(16) unsigned short Bs[3][128 * 32];
  const int tid = threadIdx.x;
  const int gx = gridDim.x;
  const int flat = blockIdx.y * gridDim.x + blockIdx.x;
  // XCD-exclusive bm partition (HW round-robins flat%8 across XCDs)
  const int xcd = flat & 7;
  const int idx = flat >> 3;
  const int bmpx = gridDim.y >> 3;
  const int bn = idx % gx;
  const int bm = xcd * bmpx + idx / gx;

  const int wid = tid >> 6, lane = tid & 63;
  const int wr = wid >> 1, wc = wid & 1;
  const int lrow = lane & 15, kq = lane >> 4;
  const int glr = lane >> 2;                          // 0..15 row within 16-row chunk
  const int glc = ((lane & 3) ^ (glr & 3)) * 8;       // pre-swizzled source chunk

  const unsigned short* Ab = A + (size_t)bm * 128 * K;
  const unsigned short* Bb = Bt + (size_t)bn * 128 * K;

  f32x4 acc[4][4];
#pragma unroll
  for (int m = 0; m < 4; ++m)
#pragma unroll
    for (int n = 0; n < 4; ++n) acc[m][n] = (f32x4){0.f, 0.f, 0.f, 0.f};

  // swizzled read byte-offsets (row*64 + (kq^row&3)*16)
  const int kqs = (kq ^ (lrow & 3)) * 16;
  int aoff[4], boff[4];
#pragma unroll
  for (int m = 0; m < 4; ++m) aoff[m] = (wr * 64 + m * 16 + lrow) * 64 + kqs;
#pragma unroll
  for (int n = 0; n < 4; ++n) boff[n] = (wc * 64 + n * 16 + lrow) * 64 + kqs;

  const int nk = K >> 5;

#define STAGE(J, kt)                                                          \
  {                                                                           \
    const unsigned short* Ak = Ab + (size_t)(kt) * 32;                        \
    const unsigned short* Bk = Bb + (size_t)(kt) * 32;                        \
    _Pragma("unroll")                                                         \
    for (int i = 0; i < 2; ++i) {                                             \
      const int rb = wid * 32 + i * 16;                                       \
      gl_lds16(Ak + (size_t)(rb + glr) * K + glc, &As[J][rb * 32]);           \
      gl_lds16(Bk + (size_t)(rb + glr) * K + glc, &Bs[J][rb * 32]);           \
    }                                                                         \
  }

// One K-step on ring slot J, waiting own vmcnt down to W (literal).
// SWAPPED operands: mfma(bfr, af) -> D cols = reg quad, rows = lane&15.
#define KSTEP(J, W, kt)                                                       \
  {                                                                           \
    asm volatile("s_waitcnt vmcnt(" #W ")" ::: "memory");                     \
    __builtin_amdgcn_sched_barrier(0);                                        \
    __builtin_amdgcn_s_barrier();                                             \
    __builtin_amdgcn_sched_barrier(0);                                        \
    bf16x8 af[4], bfr[4];                                                     \
    _Pragma("unroll")                                                         \
    for (int m = 0; m < 4; ++m)                                               \
      af[m] = *(const bf16x8*)((const char*)As[J] + aoff[m]);                 \
    _Pragma("unroll")                                                         \
    for (int n = 0; n < 4; ++n)                                               \
      bfr[n] = *(const bf16x8*)((const char*)Bs[J] + boff[n]);                \
    asm volatile("s_waitcnt lgkmcnt(0)" ::: "memory");                        \
    __builtin_amdgcn_sched_barrier(0);                                        \
    __builtin_amdgcn_s_barrier();                                             \
    __builtin_amdgcn_sched_barrier(0);                                        \
    if ((kt) + 3 < nk) STAGE(J, (kt) + 3);                                    \
    __builtin_amdgcn_sched_barrier(0);                                        \
    __builtin_amdgcn_s_setprio(1);                                            \
    _Pragma("unroll")                                                         \
    for (int m = 0; m < 4; ++m)                                               \
      _Pragma("unroll")                                                       \
      for (int n = 0; n < 4; ++n)                                             \
        acc[m][n] = __builtin_amdgcn_mfma_f32_16x16x32_bf16(bfr[n], af[m],    \
                                                            acc[m][n], 0,0,0);\
    __builtin_amdgcn_s_setprio(0);                                            \
  }

  // prologue: stage tiles 0,1,2 (12 loads/wave in flight)
  STAGE(0, 0);
  STAGE(1, 1);
  STAGE(2, 2);

  // steady state: keep 8 loads (2 tiles) in flight past each wait
  int kt0 = 0;
  for (; kt0 < nk - 3; kt0 += 3) {
    KSTEP(0, 8, kt0);
    KSTEP(1, 8, kt0 + 1);
    KSTEP(2, 8, kt0 + 2);
  }
  // tail triple: drain 8 -> 4 -> 0
  KSTEP(0, 8, nk - 3);
  KSTEP(1, 4, nk - 2);
  KSTEP(2, 0, nk - 1);

#undef KSTEP
#undef STAGE

  // Transposed-D epilogue: out_row = bm*128 + wr*64 + m*16 + lrow  (lane&15)
  //                        out_col = bn*128 + wc*64 + n*16 + kq*4 + i (reg i)
  const int rbase = bm * 128 + wr * 64;
  const int cbase = bn * 128 + wc * 64 + kq * 4;
  float gv = (EPI == 1) ? gs[0] : 0.f;
#pragma unroll
  for (int m = 0; m < 4; ++m) {
    const int row = rbase + m * 16 + lrow;
#pragma unroll
    for (int n = 0; n < 4; ++n) {
      const int colb = cbase + n * 16;
      if (EPI == 0) {
        int p = (colb < 384) ? 0 : (colb < 768) ? 1 : (colb < 1152) ? 2 : 3;
        const float* bp = (p == 0) ? b0 : (p == 1) ? b1 : (p == 2) ? b2 : b3;
        f32x4 b4 = *(const f32x4*)(bp + (colb - p * 384));
        u16x4 r;
#pragma unroll
        for (int i = 0; i < 4; ++i) r[i] = f2bf(acc[m][n][i] + b4[i]);
        *(u16x4*)(Cb + (size_t)row * N + colb) = r;
      } else {
        f32x4 b4 = *(const f32x4*)(bo + colb);
        size_t oidx = (size_t)row * N + colb;
        f32x4 x4 = *(const f32x4*)(xres + oidx);
        f32x4 o;
#pragma unroll
        for (int i = 0; i < 4; ++i) o[i] = acc[m][n][i] + b4[i] + x4[i] * gv;
        *(f32x4*)(Cf + oidx) = o;
      }
    }
  }
}

// ---------------- 3x3 attention + gate: QKVG bf16 [49152,1536] -> H bf16 [16384,1152] ----------------
__global__ __launch_bounds__(256) void attn_kernel(const unsigned short* __restrict__ QKVG,
                                                   unsigned short* __restrict__ Hout) {
  int u = blockIdx.x * 256 + threadIdx.x;   // u = t*48 + i*16 + h
  int h = u & 15;
  int ti = u >> 4;                          // = t*3 + i
  int i = ti % 3;
  int t = ti / 3;
  const unsigned short* base = QKVG + (size_t)t * 3 * 1536;
  const int co = h * 24;

  float q[24];
#pragma unroll
  for (int c = 0; c < 3; ++c) {
    u16x8 w = *(const u16x8*)(base + (size_t)i * 1536 + co + c * 8);
#pragma unroll
    for (int e = 0; e < 8; ++e) q[c * 8 + e] = bf2f(w[e]);
  }
  float s[3];
#pragma unroll
  for (int j = 0; j < 3; ++j) {
    float a = 0.f;
#pragma unroll
    for (int c = 0; c < 3; ++c) {
      u16x8 w = *(const u16x8*)(base + (size_t)j * 1536 + 384 + co + c * 8);
#pragma unroll
      for (int e = 0; e < 8; ++e) a += q[c * 8 + e] * bf2f(w[e]);
    }
    s[j] = a * 0.11785113019775793f;  // 1/sqrt(72)
  }
  float mx = fmaxf(s[0], fmaxf(s[1], s[2]));
  float e0 = __expf(s[0] - mx), e1 = __expf(s[1] - mx), e2 = __expf(s[2] - mx);
  float inv = 1.f / (e0 + e1 + e2);
  float p0 = e0 * inv, p1 = e1 * inv, p2 = e2 * inv;

  float o[24];
#pragma unroll
  for (int d = 0; d < 24; ++d) o[d] = 0.f;
  float pj[3] = {p0, p1, p2};
#pragma unroll
  for (int j = 0; j < 3; ++j) {
#pragma unroll
    for (int c = 0; c < 3; ++c) {
      u16x8 w = *(const u16x8*)(base + (size_t)j * 1536 + 768 + co + c * 8);
#pragma unroll
      for (int e = 0; e < 8; ++e) o[c * 8 + e] += pj[j] * bf2f(w[e]);
    }
  }
  unsigned short* op = Hout + (size_t)t * 1152 + (size_t)i * 384 + co;
#pragma unroll
  for (int c = 0; c < 3; ++c) {
    u16x8 w = *(const u16x8*)(base + (size_t)i * 1536 + 1152 + co + c * 8);
    u16x8 r;
#pragma unroll
    for (int e = 0; e < 8; ++e) {
      float gv = bf2f(w[e]);
      float sg = 1.f / (1.f + __expf(-gv));
      r[e] = f2bf(o[c * 8 + e] * sg);
    }
    *(u16x8*)(op + c * 8) = r;
  }
}

extern "C" void kernel_launch(void* const* d_in, const int* in_sizes, int n_in,
                              void* d_out, int out_size, void* d_ws, size_t ws_size,
                              hipStream_t stream) {
  const float* x    = (const float*)d_in[0];
  const float* ln_g = (const float*)d_in[1];
  const float* ln_b = (const float*)d_in[2];
  const float* Wq   = (const float*)d_in[3];
  const float* bq   = (const float*)d_in[4];
  const float* Wk   = (const float*)d_in[5];
  const float* bk   = (const float*)d_in[6];
  const float* Wv   = (const float*)d_in[7];
  const float* bv   = (const float*)d_in[8];
  const float* Wg   = (const float*)d_in[9];
  const float* bg   = (const float*)d_in[10];
  const float* Wo   = (const float*)d_in[11];
  const float* bo   = (const float*)d_in[12];
  const float* g    = (const float*)d_in[13];
  float* out = (float*)d_out;

  char* ws = (char*)d_ws;
  size_t off = 0;
  unsigned short* xn    = (unsigned short*)(ws + off); off += (size_t)T_ * D_ * 2;
  unsigned short* Wqkvg = (unsigned short*)(ws + off); off += (size_t)1536 * 384 * 2;
  unsigned short* Wob   = (unsigned short*)(ws + off); off += (size_t)1152 * 1152 * 2;
  unsigned short* QKVG  = (unsigned short*)(ws + off); off += (size_t)T_ * 3 * 1536 * 2;
  unsigned short* Hf    = (unsigned short*)(ws + off); off += (size_t)T_ * D_ * 2;

  ln_kernel<<<T_, 256, 0, stream>>>(x, ln_g, ln_b, xn);
  cvt_cat_wqkvg<<<(4 * 147456 + 255) / 256, 256, 0, stream>>>(Wq, Wk, Wv, Wg, Wqkvg);
  cvt_bf16<<<(1152 * 1152 + 255) / 256, 256, 0, stream>>>(Wo, Wob, 1152 * 1152);

  dim3 g1(1536 / 128, (T_ * 3) / 128);   // (12, 384) nwg=4608, grid.y%8==0
  gemm_bt<0><<<g1, 256, 0, stream>>>(xn, Wqkvg, 384, 1536, QKVG, bq, bk, bv, bg,
                                     nullptr, nullptr, nullptr, nullptr);

  attn_kernel<<<(T_ * H_ * 3) / 256, 256, 0, stream>>>(QKVG, Hf);

  dim3 g2(1152 / 128, T_ / 128);         // (9, 128) nwg=1152, grid.y%8==0
  gemm_bt<1><<<g2, 256, 0, stream>>>(Hf, Wob, 1152, 1152,
                                     nullptr, nullptr, nullptr, nullptr, nullptr,
                                     out, bo, x, g);
}

// Round 7
// 264.905 us; speedup vs baseline: 1.1610x; 1.1610x over previous
//
#include <hip/hip_runtime.h>

#define B_ 4
#define L_ 4096
#define D_ 1152
#define T_ (B_*L_)      // 16384 tokens
#define D3_ 384
#define H_ 16
#define DK3_ 24

typedef __attribute__((ext_vector_type(4))) float f32x4;
typedef __attribute__((ext_vector_type(8))) __bf16 bf16x8;
typedef __attribute__((ext_vector_type(8))) unsigned short u16x8;
typedef __attribute__((ext_vector_type(4))) unsigned short u16x4;

__device__ __forceinline__ unsigned short f2bf(float f) {
  unsigned int u = __float_as_uint(f);
  u += 0x7fffu + ((u >> 16) & 1u);   // round-to-nearest-even
  return (unsigned short)(u >> 16);
}
__device__ __forceinline__ float bf2f(unsigned short h) {
  return __uint_as_float(((unsigned int)h) << 16);
}

// async global->LDS, 16B per lane. LDS dest wave-uniform; lane l writes dest + l*16.
__device__ __forceinline__ void gl_lds16(const unsigned short* g, unsigned short* l) {
  __builtin_amdgcn_global_load_lds(
      (const __attribute__((address_space(1))) unsigned int*)g,
      (__attribute__((address_space(3))) unsigned int*)l,
      16, 0, 0);
}

// ---------------- LayerNorm: fp32 [16384,1152] -> bf16 [16384,1152] ----------------
__global__ __launch_bounds__(256) void ln_kernel(const float* __restrict__ x,
                                                 const float* __restrict__ gamma,
                                                 const float* __restrict__ beta,
                                                 unsigned short* __restrict__ xn) {
  const int row = blockIdx.x;
  const int tid = threadIdx.x;
  const float4* xr = (const float4*)(x + (size_t)row * D_);
  float4 v0 = xr[tid];
  float4 v1 = {0.f, 0.f, 0.f, 0.f};
  const bool has2 = tid < 32;
  if (has2) v1 = xr[256 + tid];
  float s  = v0.x + v0.y + v0.z + v0.w + v1.x + v1.y + v1.z + v1.w;
  float s2 = v0.x*v0.x + v0.y*v0.y + v0.z*v0.z + v0.w*v0.w
           + v1.x*v1.x + v1.y*v1.y + v1.z*v1.z + v1.w*v1.w;
#pragma unroll
  for (int o = 32; o > 0; o >>= 1) { s += __shfl_down(s, o); s2 += __shfl_down(s2, o); }
  __shared__ float red[8];
  int wid = tid >> 6, lane = tid & 63;
  if (lane == 0) { red[wid] = s; red[4 + wid] = s2; }
  __syncthreads();
  float ts  = red[0] + red[1] + red[2] + red[3];
  float ts2 = red[4] + red[5] + red[6] + red[7];
  const float inv = 1.f / (float)D_;
  float mean = ts * inv;
  float var  = ts2 * inv - mean * mean;
  float rstd = rsqrtf(var + 1e-6f);
  const float4* gm = (const float4*)gamma;
  const float4* bt = (const float4*)beta;
  unsigned short* xo = xn + (size_t)row * D_;
  {
    float4 gv = gm[tid], bv = bt[tid];
    u16x4 r;
    r[0] = f2bf((v0.x - mean) * rstd * gv.x + bv.x);
    r[1] = f2bf((v0.y - mean) * rstd * gv.y + bv.y);
    r[2] = f2bf((v0.z - mean) * rstd * gv.z + bv.z);
    r[3] = f2bf((v0.w - mean) * rstd * gv.w + bv.w);
    *(u16x4*)(xo + tid * 4) = r;
  }
  if (has2) {
    float4 gv = gm[256 + tid], bv = bt[256 + tid];
    u16x4 r;
    r[0] = f2bf((v1.x - mean) * rstd * gv.x + bv.x);
    r[1] = f2bf((v1.y - mean) * rstd * gv.y + bv.y);
    r[2] = f2bf((v1.z - mean) * rstd * gv.z + bv.z);
    r[3] = f2bf((v1.w - mean) * rstd * gv.w + bv.w);
    *(u16x4*)(xo + (256 + tid) * 4) = r;
  }
}

// ---------------- Weight converts ----------------
__global__ void cvt_cat_wqkvg(const float* __restrict__ Wq, const float* __restrict__ Wk,
                              const float* __restrict__ Wv, const float* __restrict__ Wg,
                              unsigned short* __restrict__ out) {
  int i = blockIdx.x * 256 + threadIdx.x;
  if (i >= 4 * 147456) return;
  int p = i / 147456;
  int r = i - p * 147456;
  const float* W = (p == 0) ? Wq : (p == 1) ? Wk : (p == 2) ? Wv : Wg;
  out[i] = f2bf(W[r]);
}

__global__ void cvt_bf16(const float* __restrict__ in, unsigned short* __restrict__ out, int n) {
  int i = blockIdx.x * 256 + threadIdx.x;
  if (i < n) out[i] = f2bf(in[i]);
}

// ---------------- bf16 GEMM: C[M,N] = A[M,K] @ Bt[N,K]^T (+epilogue) ----------------
// 128x128 tile, BK=32, 4 waves (2x2), 4x4 16x16x32 frags/wave.
// 3-deep LDS ring + counted vmcnt (T4).
// Conflict-free chunk swizzle: chunk = kq ^ ((row>>1)&3). Within each 16-lane
// phase the 16B-slot (4r + chunk) mod 8 covers all 8 slots exactly 2x (free);
// per-row the 4 quarters cover the full 64B (source stays 64B-coalesced).
// Requires nk % 3 == 0 (K=384 -> 12, K=1152 -> 36).

template<int EPI>
__global__ __launch_bounds__(256) void gemm_bt(
    const unsigned short* __restrict__ A, const unsigned short* __restrict__ Bt,
    int K, int N,
    unsigned short* __restrict__ Cb,
    const float* __restrict__ b0, const float* __restrict__ b1,
    const float* __restrict__ b2, const float* __restrict__ b3,
    float* __restrict__ Cf, const float* __restrict__ bo,
    const float* __restrict__ xres, const float* __restrict__ gs) {
  __shared__ __align__(16) unsigned short As[3][128 * 32];
  __shared__ __align__(16) unsigned short Bs[3][128 * 32];
  const int tid = threadIdx.x;
  const int nwg = gridDim.x * gridDim.y;
  const int flat = blockIdx.y * gridDim.x + blockIdx.x;
  const int swz = (flat & 7) * (nwg >> 3) + (flat >> 3);
  const int bn = swz % gridDim.x, bm = swz / gridDim.x;

  const int wid = tid >> 6, lane = tid & 63;
  const int wr = wid >> 1, wc = wid & 1;
  const int lrow = lane & 15, kq = lane >> 4;
  const int glr = lane >> 2;                              // 0..15 row within 16-row chunk
  const int glc = ((lane & 3) ^ ((glr >> 1) & 3)) * 8;    // pre-swizzled source chunk

  const unsigned short* Ab = A + (size_t)bm * 128 * K;
  const unsigned short* Bb = Bt + (size_t)bn * 128 * K;

  f32x4 acc[4][4];
#pragma unroll
  for (int m = 0; m < 4; ++m)
#pragma unroll
    for (int n = 0; n < 4; ++n) acc[m][n] = (f32x4){0.f, 0.f, 0.f, 0.f};

  // swizzled read byte-offsets (row*64 + (kq^((row>>1)&3))*16)
  const int kqs = (kq ^ ((lrow >> 1) & 3)) * 16;
  int aoff[4], boff[4];
#pragma unroll
  for (int m = 0; m < 4; ++m) aoff[m] = (wr * 64 + m * 16 + lrow) * 64 + kqs;
#pragma unroll
  for (int n = 0; n < 4; ++n) boff[n] = (wc * 64 + n * 16 + lrow) * 64 + kqs;

  const int nk = K >> 5;

#define STAGE(J, kt)                                                          \
  {                                                                           \
    const unsigned short* Ak = Ab + (size_t)(kt) * 32;                        \
    const unsigned short* Bk = Bb + (size_t)(kt) * 32;                        \
    _Pragma("unroll")                                                         \
    for (int i = 0; i < 2; ++i) {                                             \
      const int rb = wid * 32 + i * 16;                                       \
      gl_lds16(Ak + (size_t)(rb + glr) * K + glc, &As[J][rb * 32]);           \
      gl_lds16(Bk + (size_t)(rb + glr) * K + glc, &Bs[J][rb * 32]);           \
    }                                                                         \
  }

// One K-step on ring slot J, waiting own vmcnt down to W (literal).
#define KSTEP(J, W, kt)                                                       \
  {                                                                           \
    asm volatile("s_waitcnt vmcnt(" #W ")" ::: "memory");                     \
    __builtin_amdgcn_sched_barrier(0);                                        \
    __builtin_amdgcn_s_barrier();                                             \
    __builtin_amdgcn_sched_barrier(0);                                        \
    bf16x8 af[4], bfr[4];                                                     \
    _Pragma("unroll")                                                         \
    for (int m = 0; m < 4; ++m)                                               \
      af[m] = *(const bf16x8*)((const char*)As[J] + aoff[m]);                 \
    _Pragma("unroll")                                                         \
    for (int n = 0; n < 4; ++n)                                               \
      bfr[n] = *(const bf16x8*)((const char*)Bs[J] + boff[n]);                \
    asm volatile("s_waitcnt lgkmcnt(0)" ::: "memory");                        \
    __builtin_amdgcn_sched_barrier(0);                                        \
    __builtin_amdgcn_s_barrier();                                             \
    __builtin_amdgcn_sched_barrier(0);                                        \
    if ((kt) + 3 < nk) STAGE(J, (kt) + 3);                                    \
    __builtin_amdgcn_sched_barrier(0);                                        \
    _Pragma("unroll")                                                         \
    for (int m = 0; m < 4; ++m)                                               \
      _Pragma("unroll")                                                       \
      for (int n = 0; n < 4; ++n)                                             \
        acc[m][n] = __builtin_amdgcn_mfma_f32_16x16x32_bf16(af[m], bfr[n],    \
                                                            acc[m][n], 0,0,0);\
  }

  // prologue: stage tiles 0,1,2 (12 loads/wave in flight)
  STAGE(0, 0);
  STAGE(1, 1);
  STAGE(2, 2);

  // steady state: keep 8 loads (2 tiles) in flight past each wait
  int kt0 = 0;
  for (; kt0 < nk - 3; kt0 += 3) {
    KSTEP(0, 8, kt0);
    KSTEP(1, 8, kt0 + 1);
    KSTEP(2, 8, kt0 + 2);
  }
  // tail triple: drain 8 -> 4 -> 0
  KSTEP(0, 8, nk - 3);
  KSTEP(1, 4, nk - 2);
  KSTEP(2, 0, nk - 1);

#undef KSTEP
#undef STAGE

  // Epilogue. D layout: col = lane&15, row = (lane>>4)*4 + reg  [m89-verified]
  const int rbase = bm * 128 + wr * 64 + kq * 4;
  const int cbase = bn * 128 + wc * 64 + lrow;
  float gv = (EPI == 1) ? gs[0] : 0.f;
#pragma unroll
  for (int m = 0; m < 4; ++m) {
#pragma unroll
    for (int n = 0; n < 4; ++n) {
      int col = cbase + n * 16;
      float bias;
      if (EPI == 0) {
        int p = (col < 384) ? 0 : (col < 768) ? 1 : (col < 1152) ? 2 : 3;
        const float* bp = (p == 0) ? b0 : (p == 1) ? b1 : (p == 2) ? b2 : b3;
        bias = bp[col - p * 384];
      } else {
        bias = bo[col];
      }
#pragma unroll
      for (int i = 0; i < 4; ++i) {
        int row = rbase + m * 16 + i;
        float val = acc[m][n][i] + bias;
        if (EPI == 0) {
          Cb[(size_t)row * N + col] = f2bf(val);
        } else {
          size_t idx = (size_t)row * N + col;
          Cf[idx] = val + xres[idx] * gv;
        }
      }
    }
  }
}

// ---------------- 3x3 attention + gate: QKVG bf16 [49152,1536] -> H bf16 [16384,1152] ----------------
__global__ __launch_bounds__(256) void attn_kernel(const unsigned short* __restrict__ QKVG,
                                                   unsigned short* __restrict__ Hout) {
  int u = blockIdx.x * 256 + threadIdx.x;   // u = t*48 + i*16 + h
  int h = u & 15;
  int ti = u >> 4;                          // = t*3 + i
  int i = ti % 3;
  int t = ti / 3;
  const unsigned short* base = QKVG + (size_t)t * 3 * 1536;
  const int co = h * 24;

  float q[24];
#pragma unroll
  for (int c = 0; c < 3; ++c) {
    u16x8 w = *(const u16x8*)(base + (size_t)i * 1536 + co + c * 8);
#pragma unroll
    for (int e = 0; e < 8; ++e) q[c * 8 + e] = bf2f(w[e]);
  }
  float s[3];
#pragma unroll
  for (int j = 0; j < 3; ++j) {
    float a = 0.f;
#pragma unroll
    for (int c = 0; c < 3; ++c) {
      u16x8 w = *(const u16x8*)(base + (size_t)j * 1536 + 384 + co + c * 8);
#pragma unroll
      for (int e = 0; e < 8; ++e) a += q[c * 8 + e] * bf2f(w[e]);
    }
    s[j] = a * 0.11785113019775793f;  // 1/sqrt(72)
  }
  float mx = fmaxf(s[0], fmaxf(s[1], s[2]));
  float e0 = __expf(s[0] - mx), e1 = __expf(s[1] - mx), e2 = __expf(s[2] - mx);
  float inv = 1.f / (e0 + e1 + e2);
  float p0 = e0 * inv, p1 = e1 * inv, p2 = e2 * inv;

  float o[24];
#pragma unroll
  for (int d = 0; d < 24; ++d) o[d] = 0.f;
  float pj[3] = {p0, p1, p2};
#pragma unroll
  for (int j = 0; j < 3; ++j) {
#pragma unroll
    for (int c = 0; c < 3; ++c) {
      u16x8 w = *(const u16x8*)(base + (size_t)j * 1536 + 768 + co + c * 8);
#pragma unroll
      for (int e = 0; e < 8; ++e) o[c * 8 + e] += pj[j] * bf2f(w[e]);
    }
  }
  unsigned short* op = Hout + (size_t)t * 1152 + (size_t)i * 384 + co;
#pragma unroll
  for (int c = 0; c < 3; ++c) {
    u16x8 w = *(const u16x8*)(base + (size_t)i * 1536 + 1152 + co + c * 8);
    u16x8 r;
#pragma unroll
    for (int e = 0; e < 8; ++e) {
      float gv = bf2f(w[e]);
      float sg = 1.f / (1.f + __expf(-gv));
      r[e] = f2bf(o[c * 8 + e] * sg);
    }
    *(u16x8*)(op + c * 8) = r;
  }
}

extern "C" void kernel_launch(void* const* d_in, const int* in_sizes, int n_in,
                              void* d_out, int out_size, void* d_ws, size_t ws_size,
                              hipStream_t stream) {
  const float* x    = (const float*)d_in[0];
  const float* ln_g = (const float*)d_in[1];
  const float* ln_b = (const float*)d_in[2];
  const float* Wq   = (const float*)d_in[3];
  const float* bq   = (const float*)d_in[4];
  const float* Wk   = (const float*)d_in[5];
  const float* bk   = (const float*)d_in[6];
  const float* Wv   = (const float*)d_in[7];
  const float* bv   = (const float*)d_in[8];
  const float* Wg   = (const float*)d_in[9];
  const float* bg   = (const float*)d_in[10];
  const float* Wo   = (const float*)d_in[11];
  const float* bo   = (const float*)d_in[12];
  const float* g    = (const float*)d_in[13];
  float* out = (float*)d_out;

  char* ws = (char*)d_ws;
  size_t off = 0;
  unsigned short* xn    = (unsigned short*)(ws + off); off += (size_t)T_ * D_ * 2;
  unsigned short* Wqkvg = (unsigned short*)(ws + off); off += (size_t)1536 * 384 * 2;
  unsigned short* Wob   = (unsigned short*)(ws + off); off += (size_t)1152 * 1152 * 2;
  unsigned short* QKVG  = (unsigned short*)(ws + off); off += (size_t)T_ * 3 * 1536 * 2;
  unsigned short* Hf    = (unsigned short*)(ws + off); off += (size_t)T_ * D_ * 2;

  ln_kernel<<<T_, 256, 0, stream>>>(x, ln_g, ln_b, xn);
  cvt_cat_wqkvg<<<(4 * 147456 + 255) / 256, 256, 0, stream>>>(Wq, Wk, Wv, Wg, Wqkvg);
  cvt_bf16<<<(1152 * 1152 + 255) / 256, 256, 0, stream>>>(Wo, Wob, 1152 * 1152);

  dim3 g1(1536 / 128, (T_ * 3) / 128);   // (12, 384) nwg=4608
  gemm_bt<0><<<g1, 256, 0, stream>>>(xn, Wqkvg, 384, 1536, QKVG, bq, bk, bv, bg,
                                     nullptr, nullptr, nullptr, nullptr);

  attn_kernel<<<(T_ * H_ * 3) / 256, 256, 0, stream>>>(QKVG, Hf);

  dim3 g2(1152 / 128, T_ / 128);         // (9, 128) nwg=1152
  gemm_bt<1><<<g2, 256, 0, stream>>>(Hf, Wob, 1152, 1152,
                                     nullptr, nullptr, nullptr, nullptr, nullptr,
                                     out, bo, x, g);
}